// Round 1
// baseline (2379.755 us; speedup 1.0000x reference)
//
#include <hip/hip_runtime.h>

// VarianceAdaptor: 3x (conv1d->relu->LN->conv1d->relu->LN->linear) predictors,
// embedding adds between them, then length-regulate.
// Shapes fixed: B=32, S=512, D=F=512, K=3, T=4096, NB=256.
// Round 1: fp32 correctness baseline. Conv = LDS-tiled direct conv.

#define B_ 32
#define S_ 512
#define D_ 512
#define F_ 512
#define T_ 4096
#define CTS 16  // s-rows per conv block

// ---------------- conv: Y[b,s,f] = sum_{k,d} X[b,s+k-1,d] * W[k,d,f] (raw) ---
__global__ __launch_bounds__(256) void conv_k(const float* __restrict__ X,
                                              const float* __restrict__ W,
                                              float* __restrict__ Y) {
  __shared__ float xs[CTS + 2][D_];
  const int b  = blockIdx.x >> 5;           // 512/16 = 32 s-tiles per batch
  const int st = (blockIdx.x & 31) * CTS;
  const int t  = threadIdx.x;
  const float* Xb = X + (size_t)b * S_ * D_;
  // stage rows st-1 .. st+16 (zero-padded at batch edges, SAME conv)
  #pragma unroll
  for (int j = 0; j < CTS + 2; ++j) {
    const int s = st - 1 + j;
    float2 v = make_float2(0.f, 0.f);
    if (s >= 0 && s < S_) v = *(const float2*)(Xb + (size_t)s * D_ + t * 2);
    *(float2*)(&xs[j][t * 2]) = v;
  }
  __syncthreads();
  const int f0 = (t & 127) * 4;   // 128 f-groups of 4
  const int rg = (t >> 7) * 8;    // 2 row-groups of 8
  float acc[8][4];
  #pragma unroll
  for (int r = 0; r < 8; ++r)
    #pragma unroll
    for (int c = 0; c < 4; ++c) acc[r][c] = 0.f;

  for (int d = 0; d < D_; ++d) {
    float xv[10];
    #pragma unroll
    for (int j = 0; j < 10; ++j) xv[j] = xs[rg + j][d];  // wave-uniform: broadcast
    #pragma unroll
    for (int k = 0; k < 3; ++k) {
      const float4 w4 = *(const float4*)(W + ((size_t)k * D_ + d) * F_ + f0);
      #pragma unroll
      for (int r = 0; r < 8; ++r) {
        acc[r][0] += xv[r + k] * w4.x;
        acc[r][1] += xv[r + k] * w4.y;
        acc[r][2] += xv[r + k] * w4.z;
        acc[r][3] += xv[r + k] * w4.w;
      }
    }
  }
  float* Yb = Y + ((size_t)b * S_ + st + rg) * F_ + f0;
  #pragma unroll
  for (int r = 0; r < 8; ++r)
    *(float4*)(Yb + (size_t)r * F_) =
        make_float4(acc[r][0], acc[r][1], acc[r][2], acc[r][3]);
}

// ------------- in-place bias + relu + layernorm over f (one row per block) ---
__global__ __launch_bounds__(256) void ln_k(float* __restrict__ Y,
                                            const float* __restrict__ bias,
                                            const float* __restrict__ g,
                                            const float* __restrict__ be) {
  const int row = blockIdx.x;
  const int t   = threadIdx.x;
  float* p = Y + (size_t)row * F_;
  float2 v = *(float2*)(p + t * 2);
  v.x = fmaxf(v.x + bias[t * 2], 0.f);
  v.y = fmaxf(v.y + bias[t * 2 + 1], 0.f);
  __shared__ float red[6];
  float s = v.x + v.y;
  #pragma unroll
  for (int o = 32; o > 0; o >>= 1) s += __shfl_down(s, o, 64);
  const int lane = t & 63, w = t >> 6;
  if (lane == 0) red[w] = s;
  __syncthreads();
  if (t == 0) red[4] = red[0] + red[1] + red[2] + red[3];
  __syncthreads();
  const float mean = red[4] * (1.f / F_);
  const float dx = v.x - mean, dy = v.y - mean;
  float q = dx * dx + dy * dy;
  #pragma unroll
  for (int o = 32; o > 0; o >>= 1) q += __shfl_down(q, o, 64);
  __syncthreads();
  if (lane == 0) red[w] = q;
  __syncthreads();
  if (t == 0) red[5] = red[0] + red[1] + red[2] + red[3];
  __syncthreads();
  const float inv = rsqrtf(red[5] * (1.f / F_) + 1e-5f);
  float2 o2;
  o2.x = dx * inv * g[t * 2]     + be[t * 2];
  o2.y = dy * inv * g[t * 2 + 1] + be[t * 2 + 1];
  *(float2*)(p + t * 2) = o2;
}

// ------------- pred[row] = mask ? 0 : dot(h[row,:], wl) + bl  (wave per row) -
__global__ __launch_bounds__(256) void lin_k(const float* __restrict__ H,
                                             const float* __restrict__ wl,
                                             const float* __restrict__ bl,
                                             const unsigned char* __restrict__ mask,
                                             float* __restrict__ pred) {
  const int wid  = threadIdx.x >> 6;
  const int lane = threadIdx.x & 63;
  const int row  = blockIdx.x * 4 + wid;
  const float* p = H + (size_t)row * F_;
  float s = 0.f;
  #pragma unroll
  for (int j = 0; j < 8; ++j) s += p[lane + j * 64] * wl[lane + j * 64];
  #pragma unroll
  for (int o = 32; o > 0; o >>= 1) s += __shfl_down(s, o, 64);
  if (lane == 0) pred[row] = mask[row] ? 0.f : (s + bl[0]);
}

// ------------- out[row,:] = in[row,:] + emb[searchsorted_left(bins, truth)] --
__global__ __launch_bounds__(128) void addemb_k(const float* __restrict__ in,
                                                const float* __restrict__ truth,
                                                const float* __restrict__ bins,
                                                const float* __restrict__ emb,
                                                float* __restrict__ out) {
  const int row = blockIdx.x;  // b*S + s
  __shared__ int sidx;
  if (threadIdx.x == 0) {
    const float v = truth[row];
    int lo = 0, hi = 255;  // NB-1 bins
    while (lo < hi) {
      const int mid = (lo + hi) >> 1;
      if (bins[mid] < v) lo = mid + 1; else hi = mid;
    }
    sidx = lo;  // #{bins < v} == searchsorted side='left'
  }
  __syncthreads();
  const int e = sidx;
  float4 a = *(const float4*)(in + (size_t)row * D_ + threadIdx.x * 4);
  const float4 b4 = *(const float4*)(emb + (size_t)e * D_ + threadIdx.x * 4);
  a.x += b4.x; a.y += b4.y; a.z += b4.z; a.w += b4.w;
  *(float4*)(out + (size_t)row * D_ + threadIdx.x * 4) = a;
}

// ------------- inclusive cumsum of durations per batch; mel_len as float -----
__global__ __launch_bounds__(512) void scan_k(const int* __restrict__ dur,
                                              int* __restrict__ cum,
                                              float* __restrict__ mel_len) {
  __shared__ int sh[S_];
  const int b = blockIdx.x, t = threadIdx.x;
  sh[t] = dur[b * S_ + t];
  __syncthreads();
  for (int off = 1; off < S_; off <<= 1) {
    const int add = (t >= off) ? sh[t - off] : 0;
    __syncthreads();
    sh[t] += add;
    __syncthreads();
  }
  cum[b * S_ + t] = sh[t];
  if (t == S_ - 1) mel_len[b] = (float)sh[t];
}

// ------------- length regulate: out[b,pos,:] = valid ? x[b,idx,:] : 0 --------
__global__ __launch_bounds__(128) void gather_k(const float* __restrict__ X,
                                                const int* __restrict__ cum,
                                                float* __restrict__ out) {
  const int b   = blockIdx.x >> 12;    // T=4096 positions per batch
  const int pos = blockIdx.x & (T_ - 1);
  __shared__ int sidx, svalid;
  if (threadIdx.x == 0) {
    const int* c = cum + b * S_;
    int lo = 0, hi = S_;
    while (lo < hi) {                  // upper_bound: first c[i] > pos
      const int mid = (lo + hi) >> 1;
      if (c[mid] <= pos) lo = mid + 1; else hi = mid;
    }
    sidx = (lo < S_ - 1) ? lo : (S_ - 1);
    svalid = (pos < c[S_ - 1]) ? 1 : 0;
  }
  __syncthreads();
  float4 v = make_float4(0.f, 0.f, 0.f, 0.f);
  if (svalid) v = *(const float4*)(X + ((size_t)b * S_ + sidx) * D_ + threadIdx.x * 4);
  *(float4*)(out + ((size_t)b * T_ + pos) * D_ + threadIdx.x * 4) = v;
}

// ------------- mel_mask bool -> float ---------------------------------------
__global__ __launch_bounds__(256) void maskcopy_k(const unsigned char* __restrict__ m,
                                                  float* __restrict__ out) {
  const int i = blockIdx.x * 256 + threadIdx.x;
  out[i] = m[i] ? 1.f : 0.f;
}

extern "C" void kernel_launch(void* const* d_in, const int* in_sizes, int n_in,
                              void* d_out, int out_size, void* d_ws, size_t ws_size,
                              hipStream_t stream) {
  const float* x            = (const float*)d_in[0];
  const unsigned char* srcm = (const unsigned char*)d_in[1];
  const unsigned char* melm = (const unsigned char*)d_in[2];
  const float* pitch_truth  = (const float*)d_in[3];
  const float* energy_truth = (const float*)d_in[4];
  const int*   dur          = (const int*)d_in[5];
  const float* conv1_w = (const float*)d_in[6];
  const float* conv1_b = (const float*)d_in[7];
  const float* ln1_g   = (const float*)d_in[8];
  const float* ln1_b   = (const float*)d_in[9];
  const float* conv2_w = (const float*)d_in[10];
  const float* conv2_b = (const float*)d_in[11];
  const float* ln2_g   = (const float*)d_in[12];
  const float* ln2_b   = (const float*)d_in[13];
  const float* lin_w   = (const float*)d_in[14];
  const float* lin_b   = (const float*)d_in[15];
  const float* pitch_emb   = (const float*)d_in[16];
  const float* energy_emb  = (const float*)d_in[17];
  const float* pitch_bins  = (const float*)d_in[18];
  const float* energy_bins = (const float*)d_in[19];

  float* out      = (float*)d_out;
  float* x_out    = out;                               // 32*4096*512
  float* p_pitch  = out + (size_t)B_ * T_ * D_;        // 67108864
  float* p_energy = p_pitch + B_ * S_;
  float* p_dur    = p_energy + B_ * S_;
  float* p_mellen = p_dur + B_ * S_;
  float* p_mask   = p_mellen + B_;

  // workspace: xa (33.5MB) | y (33.5MB) | y2 (33.5MB) | cum (64KB)  ~= 100.8MB
  float* xa = (float*)d_ws;
  float* y  = xa + (size_t)B_ * S_ * D_;
  float* y2 = y  + (size_t)B_ * S_ * F_;
  int*   cum = (int*)(y2 + (size_t)B_ * S_ * F_);

  const dim3 blk256(256), blk128(128), blk512(512);
  const dim3 convGrid(B_ * (S_ / CTS));      // 1024
  const dim3 rowGrid(B_ * S_);               // 16384
  const dim3 linGrid(B_ * S_ / 4);           // 4096

  auto predictor = [&](const float* in, int i, float* pred) {
    const float* w1 = conv1_w + (size_t)i * 3 * D_ * F_;
    const float* w2 = conv2_w + (size_t)i * 3 * F_ * F_;
    conv_k<<<convGrid, blk256, 0, stream>>>(in, w1, y);
    ln_k<<<rowGrid, blk256, 0, stream>>>(y, conv1_b + (size_t)i * F_,
                                         ln1_g + (size_t)i * F_, ln1_b + (size_t)i * F_);
    conv_k<<<convGrid, blk256, 0, stream>>>(y, w2, y2);
    ln_k<<<rowGrid, blk256, 0, stream>>>(y2, conv2_b + (size_t)i * F_,
                                         ln2_g + (size_t)i * F_, ln2_b + (size_t)i * F_);
    lin_k<<<linGrid, blk256, 0, stream>>>(y2, lin_w + (size_t)i * F_, lin_b + i,
                                          srcm, pred);
  };

  predictor(x, 0, p_pitch);
  addemb_k<<<rowGrid, blk128, 0, stream>>>(x, pitch_truth, pitch_bins, pitch_emb, xa);
  predictor(xa, 1, p_energy);
  addemb_k<<<rowGrid, blk128, 0, stream>>>(xa, energy_truth, energy_bins, energy_emb, xa);
  predictor(xa, 2, p_dur);

  scan_k<<<dim3(B_), blk512, 0, stream>>>(dur, cum, p_mellen);
  gather_k<<<dim3(B_ * T_), blk128, 0, stream>>>(xa, cum, x_out);
  maskcopy_k<<<dim3((B_ * T_) / 256), blk256, 0, stream>>>(melm, p_mask);
}

// Round 2
// 544.079 us; speedup vs baseline: 4.3739x; 4.3739x over previous
//
#include <hip/hip_runtime.h>
#include <hip/hip_bf16.h>

// VarianceAdaptor: 3x (conv1d->relu->LN->conv1d->relu->LN->linear) predictors,
// embedding adds between them, then length-regulate.
// Shapes fixed: B=32, S=512, D=F=512, K=3, T=4096, NB=256.
// Round 2: conv -> bf16 MFMA GEMM (m97 structure: 128^2 tile, 4 waves,
// 16x16x32 MFMA, global_load_lds width 16, B^T weights). Exact fp32 path for
// x_out/mel_len unchanged.

#define B_ 32
#define S_ 512
#define D_ 512
#define F_ 512
#define T_ 4096
#define SP_ 514           // padded rows per batch (row0 and row513 are zeros)
#define KK_ 1536          // 3*512 contraction length

typedef __attribute__((ext_vector_type(8))) short bf16x8;
typedef __attribute__((ext_vector_type(4))) float f32x4;

// ---------------- zero the pad rows of P (once per launch) -------------------
__global__ __launch_bounds__(128) void zeropad_k(__hip_bfloat16* __restrict__ P) {
  const int b = blockIdx.x >> 1;
  const int r = (blockIdx.x & 1) ? (SP_ - 1) : 0;
  *(ushort4*)((unsigned short*)P + ((size_t)b * SP_ + r) * D_ + threadIdx.x * 4) =
      make_ushort4(0, 0, 0, 0);
}

// ---------------- fp32 [B][512][512] -> bf16 padded P rows 1..512 ------------
__global__ __launch_bounds__(128) void topad_k(const float* __restrict__ in,
                                               __hip_bfloat16* __restrict__ P) {
  const int row = blockIdx.x;          // b*512 + s
  const int b = row >> 9, s = row & 511;
  const float4 v = *(const float4*)(in + (size_t)row * D_ + threadIdx.x * 4);
  __hip_bfloat16 h0 = __float2bfloat16(v.x), h1 = __float2bfloat16(v.y);
  __hip_bfloat16 h2 = __float2bfloat16(v.z), h3 = __float2bfloat16(v.w);
  ushort4 u = make_ushort4(*(unsigned short*)&h0, *(unsigned short*)&h1,
                           *(unsigned short*)&h2, *(unsigned short*)&h3);
  *(ushort4*)((unsigned short*)P + ((size_t)b * SP_ + s + 1) * D_ + threadIdx.x * 4) = u;
}

// ---------------- W [1536][512] fp32 -> WT [512][1536] bf16 (6 matrices) -----
__global__ __launch_bounds__(256) void wtrans_k(const float* __restrict__ W1,
                                                const float* __restrict__ W2,
                                                __hip_bfloat16* __restrict__ WT1,
                                                __hip_bfloat16* __restrict__ WT2) {
  __shared__ float tb[64][65];
  const int bid = blockIdx.x;          // w*192 + kt*8 + ft
  const int w = bid / 192;
  const int kt = (bid % 192) >> 3;     // 24 kk-tiles of 64
  const int ft = bid & 7;              // 8 f-tiles of 64
  const float* src = (w < 3) ? (W1 + (size_t)w * KK_ * F_)
                             : (W2 + (size_t)(w - 3) * KK_ * F_);
  __hip_bfloat16* dst = (w < 3) ? (WT1 + (size_t)w * KK_ * F_)
                                : (WT2 + (size_t)(w - 3) * KK_ * F_);
  const int ty = threadIdx.x >> 4, tx = threadIdx.x & 15;
  #pragma unroll
  for (int j = 0; j < 4; ++j) {
    const int r = ty + j * 16;         // kk within tile
    const float4 v = *(const float4*)(src + (size_t)(kt * 64 + r) * F_ + ft * 64 + tx * 4);
    tb[r][tx * 4 + 0] = v.x; tb[r][tx * 4 + 1] = v.y;
    tb[r][tx * 4 + 2] = v.z; tb[r][tx * 4 + 3] = v.w;
  }
  __syncthreads();
  #pragma unroll
  for (int j = 0; j < 4; ++j) {
    const int r = ty + j * 16;         // f within tile
    __hip_bfloat16 h0 = __float2bfloat16(tb[tx * 4 + 0][r]);
    __hip_bfloat16 h1 = __float2bfloat16(tb[tx * 4 + 1][r]);
    __hip_bfloat16 h2 = __float2bfloat16(tb[tx * 4 + 2][r]);
    __hip_bfloat16 h3 = __float2bfloat16(tb[tx * 4 + 3][r]);
    ushort4 u = make_ushort4(*(unsigned short*)&h0, *(unsigned short*)&h1,
                             *(unsigned short*)&h2, *(unsigned short*)&h3);
    *(ushort4*)((unsigned short*)dst + (size_t)(ft * 64 + r) * KK_ + kt * 64 + tx * 4) = u;
  }
}

// ---------------- conv as bf16 MFMA GEMM (m97 structure) ---------------------
// Y[b*512+st+i][f0+j] = sum_{shift,d} P[b][st+shift+i][d] * WT[f0+j][shift*512+d]
__global__ __launch_bounds__(256) void convmm_k(const __hip_bfloat16* __restrict__ P,
                                                const __hip_bfloat16* __restrict__ WT,
                                                float* __restrict__ Y) {
  __shared__ __align__(16) __hip_bfloat16 As[128 * 32];  // 8 KB  [row][k]
  __shared__ __align__(16) __hip_bfloat16 Bs[128 * 32];  // 8 KB  [f][k]
  const int nt = blockIdx.x & 3;       // 4 N-tiles (f)
  const int mt = blockIdx.x >> 2;      // 128 M-tiles (rows)
  const int b  = mt >> 2;              // 4 M-tiles per batch
  const int st = (mt & 3) * 128;
  const int f0 = nt * 128;
  const int t = threadIdx.x;
  const int lane = t & 63;
  const int wave = t >> 6;
  const int wm = (wave >> 1) * 64;     // 2x2 wave grid, 64x64 each
  const int wn = (wave & 1) * 64;

  f32x4 acc[4][4];
  #pragma unroll
  for (int m = 0; m < 4; ++m)
    #pragma unroll
    for (int n = 0; n < 4; ++n) acc[m][n] = (f32x4){0.f, 0.f, 0.f, 0.f};

  const __hip_bfloat16* Xb = P + (size_t)b * SP_ * D_;
  const int slot0 = wave * 64 + lane;

  for (int kk = 0; kk < 48; ++kk) {
    const int shift = kk >> 4;               // 0..2 (conv tap)
    const int d0 = (kk & 15) * 32;           // d-tile
    const int kb = shift * 512 + d0;         // kk base for WT
    #pragma unroll
    for (int j = 0; j < 2; ++j) {
      const int slot = j * 256 + slot0;      // 512 slots of 16B per tile
      const int row = slot >> 2, cg = (slot & 3) * 8;
      const __hip_bfloat16* ga = Xb + (size_t)(st + shift + row) * D_ + d0 + cg;
      __builtin_amdgcn_global_load_lds(
          (const __attribute__((address_space(1))) void*)ga,
          (__attribute__((address_space(3))) void*)((char*)As + (j * 256 + wave * 64) * 16),
          16, 0, 0);
      const __hip_bfloat16* gb = WT + (size_t)(f0 + row) * KK_ + kb + cg;
      __builtin_amdgcn_global_load_lds(
          (const __attribute__((address_space(1))) void*)gb,
          (__attribute__((address_space(3))) void*)((char*)Bs + (j * 256 + wave * 64) * 16),
          16, 0, 0);
    }
    __syncthreads();
    const int rA = lane & 15;
    const int kc = (lane >> 4) * 16;         // byte offset of 8-elem K-chunk
    bf16x8 af[4], bfr[4];
    #pragma unroll
    for (int m = 0; m < 4; ++m)
      af[m] = *(const bf16x8*)((const char*)As + (wm + m * 16 + rA) * 64 + kc);
    #pragma unroll
    for (int n = 0; n < 4; ++n)
      bfr[n] = *(const bf16x8*)((const char*)Bs + (wn + n * 16 + rA) * 64 + kc);
    #pragma unroll
    for (int m = 0; m < 4; ++m)
      #pragma unroll
      for (int n = 0; n < 4; ++n)
        acc[m][n] = __builtin_amdgcn_mfma_f32_16x16x32_bf16(af[m], bfr[n], acc[m][n], 0, 0, 0);
    __syncthreads();
  }
  // C/D layout: col = lane&15, row = (lane>>4)*4 + reg   [m89-verified]
  const int col = lane & 15;
  const int r0 = (lane >> 4) * 4;
  #pragma unroll
  for (int m = 0; m < 4; ++m) {
    #pragma unroll
    for (int n = 0; n < 4; ++n) {
      float* yp = Y + ((size_t)b * S_ + st + wm + m * 16 + r0) * F_ + f0 + wn + n * 16 + col;
      #pragma unroll
      for (int r = 0; r < 4; ++r) yp[(size_t)r * F_] = acc[m][n][r];
    }
  }
}

// ------------- bias + relu + layernorm; fp32 in, bf16-padded out (into P) ----
__global__ __launch_bounds__(256) void ln_pad_k(const float* __restrict__ Y,
                                                const float* __restrict__ bias,
                                                const float* __restrict__ g,
                                                const float* __restrict__ be,
                                                __hip_bfloat16* __restrict__ P) {
  const int row = blockIdx.x;          // b*512 + s
  const int t   = threadIdx.x;
  const float* p = Y + (size_t)row * F_;
  float2 v = *(const float2*)(p + t * 2);
  v.x = fmaxf(v.x + bias[t * 2], 0.f);
  v.y = fmaxf(v.y + bias[t * 2 + 1], 0.f);
  __shared__ float red[6];
  float s = v.x + v.y;
  #pragma unroll
  for (int o = 32; o > 0; o >>= 1) s += __shfl_down(s, o, 64);
  const int lane = t & 63, w = t >> 6;
  if (lane == 0) red[w] = s;
  __syncthreads();
  if (t == 0) red[4] = red[0] + red[1] + red[2] + red[3];
  __syncthreads();
  const float mean = red[4] * (1.f / F_);
  const float dx = v.x - mean, dy = v.y - mean;
  float q = dx * dx + dy * dy;
  #pragma unroll
  for (int o = 32; o > 0; o >>= 1) q += __shfl_down(q, o, 64);
  __syncthreads();
  if (lane == 0) red[w] = q;
  __syncthreads();
  if (t == 0) red[5] = red[0] + red[1] + red[2] + red[3];
  __syncthreads();
  const float inv = rsqrtf(red[5] * (1.f / F_) + 1e-5f);
  __hip_bfloat16 h0 = __float2bfloat16(dx * inv * g[t * 2]     + be[t * 2]);
  __hip_bfloat16 h1 = __float2bfloat16(dy * inv * g[t * 2 + 1] + be[t * 2 + 1]);
  ushort2 u = make_ushort2(*(unsigned short*)&h0, *(unsigned short*)&h1);
  const int b = row >> 9, sr = row & 511;
  *(ushort2*)((unsigned short*)P + ((size_t)b * SP_ + sr + 1) * D_ + t * 2) = u;
}

// ------------- bias + relu + layernorm in place (fp32) -----------------------
__global__ __launch_bounds__(256) void ln_f32_k(float* __restrict__ Y,
                                                const float* __restrict__ bias,
                                                const float* __restrict__ g,
                                                const float* __restrict__ be) {
  const int row = blockIdx.x;
  const int t   = threadIdx.x;
  float* p = Y + (size_t)row * F_;
  float2 v = *(float2*)(p + t * 2);
  v.x = fmaxf(v.x + bias[t * 2], 0.f);
  v.y = fmaxf(v.y + bias[t * 2 + 1], 0.f);
  __shared__ float red[6];
  float s = v.x + v.y;
  #pragma unroll
  for (int o = 32; o > 0; o >>= 1) s += __shfl_down(s, o, 64);
  const int lane = t & 63, w = t >> 6;
  if (lane == 0) red[w] = s;
  __syncthreads();
  if (t == 0) red[4] = red[0] + red[1] + red[2] + red[3];
  __syncthreads();
  const float mean = red[4] * (1.f / F_);
  const float dx = v.x - mean, dy = v.y - mean;
  float q = dx * dx + dy * dy;
  #pragma unroll
  for (int o = 32; o > 0; o >>= 1) q += __shfl_down(q, o, 64);
  __syncthreads();
  if (lane == 0) red[w] = q;
  __syncthreads();
  if (t == 0) red[5] = red[0] + red[1] + red[2] + red[3];
  __syncthreads();
  const float inv = rsqrtf(red[5] * (1.f / F_) + 1e-5f);
  float2 o2;
  o2.x = dx * inv * g[t * 2]     + be[t * 2];
  o2.y = dy * inv * g[t * 2 + 1] + be[t * 2 + 1];
  *(float2*)(p + t * 2) = o2;
}

// ------------- pred[row] = mask ? 0 : dot(h[row,:], wl) + bl  (wave per row) -
__global__ __launch_bounds__(256) void lin_k(const float* __restrict__ H,
                                             const float* __restrict__ wl,
                                             const float* __restrict__ bl,
                                             const unsigned char* __restrict__ mask,
                                             float* __restrict__ pred) {
  const int wid  = threadIdx.x >> 6;
  const int lane = threadIdx.x & 63;
  const int row  = blockIdx.x * 4 + wid;
  const float* p = H + (size_t)row * F_;
  float s = 0.f;
  #pragma unroll
  for (int j = 0; j < 8; ++j) s += p[lane + j * 64] * wl[lane + j * 64];
  #pragma unroll
  for (int o = 32; o > 0; o >>= 1) s += __shfl_down(s, o, 64);
  if (lane == 0) pred[row] = mask[row] ? 0.f : (s + bl[0]);
}

// ------------- out[row,:] = in[row,:] + emb[searchsorted_left(bins, truth)] --
__global__ __launch_bounds__(128) void addemb_k(const float* __restrict__ in,
                                                const float* __restrict__ truth,
                                                const float* __restrict__ bins,
                                                const float* __restrict__ emb,
                                                float* __restrict__ out) {
  const int row = blockIdx.x;  // b*S + s
  __shared__ int sidx;
  if (threadIdx.x == 0) {
    const float v = truth[row];
    int lo = 0, hi = 255;  // NB-1 bins
    while (lo < hi) {
      const int mid = (lo + hi) >> 1;
      if (bins[mid] < v) lo = mid + 1; else hi = mid;
    }
    sidx = lo;  // #{bins < v} == searchsorted side='left'
  }
  __syncthreads();
  const int e = sidx;
  float4 a = *(const float4*)(in + (size_t)row * D_ + threadIdx.x * 4);
  const float4 b4 = *(const float4*)(emb + (size_t)e * D_ + threadIdx.x * 4);
  a.x += b4.x; a.y += b4.y; a.z += b4.z; a.w += b4.w;
  *(float4*)(out + (size_t)row * D_ + threadIdx.x * 4) = a;
}

// ------------- inclusive cumsum of durations per batch; mel_len as float -----
__global__ __launch_bounds__(512) void scan_k(const int* __restrict__ dur,
                                              int* __restrict__ cum,
                                              float* __restrict__ mel_len) {
  __shared__ int sh[S_];
  const int b = blockIdx.x, t = threadIdx.x;
  sh[t] = dur[b * S_ + t];
  __syncthreads();
  for (int off = 1; off < S_; off <<= 1) {
    const int add = (t >= off) ? sh[t - off] : 0;
    __syncthreads();
    sh[t] += add;
    __syncthreads();
  }
  cum[b * S_ + t] = sh[t];
  if (t == S_ - 1) mel_len[b] = (float)sh[t];
}

// ------------- length regulate: out[b,pos,:] = valid ? x[b,idx,:] : 0 --------
__global__ __launch_bounds__(128) void gather_k(const float* __restrict__ X,
                                                const int* __restrict__ cum,
                                                float* __restrict__ out) {
  const int b   = blockIdx.x >> 12;    // T=4096 positions per batch
  const int pos = blockIdx.x & (T_ - 1);
  __shared__ int sidx, svalid;
  if (threadIdx.x == 0) {
    const int* c = cum + b * S_;
    int lo = 0, hi = S_;
    while (lo < hi) {                  // upper_bound: first c[i] > pos
      const int mid = (lo + hi) >> 1;
      if (c[mid] <= pos) lo = mid + 1; else hi = mid;
    }
    sidx = (lo < S_ - 1) ? lo : (S_ - 1);
    svalid = (pos < c[S_ - 1]) ? 1 : 0;
  }
  __syncthreads();
  float4 v = make_float4(0.f, 0.f, 0.f, 0.f);
  if (svalid) v = *(const float4*)(X + ((size_t)b * S_ + sidx) * D_ + threadIdx.x * 4);
  *(float4*)(out + ((size_t)b * T_ + pos) * D_ + threadIdx.x * 4) = v;
}

// ------------- mel_mask bool -> float ---------------------------------------
__global__ __launch_bounds__(256) void maskcopy_k(const unsigned char* __restrict__ m,
                                                  float* __restrict__ out) {
  const int i = blockIdx.x * 256 + threadIdx.x;
  out[i] = m[i] ? 1.f : 0.f;
}

extern "C" void kernel_launch(void* const* d_in, const int* in_sizes, int n_in,
                              void* d_out, int out_size, void* d_ws, size_t ws_size,
                              hipStream_t stream) {
  const float* x            = (const float*)d_in[0];
  const unsigned char* srcm = (const unsigned char*)d_in[1];
  const unsigned char* melm = (const unsigned char*)d_in[2];
  const float* pitch_truth  = (const float*)d_in[3];
  const float* energy_truth = (const float*)d_in[4];
  const int*   dur          = (const int*)d_in[5];
  const float* conv1_w = (const float*)d_in[6];
  const float* conv1_b = (const float*)d_in[7];
  const float* ln1_g   = (const float*)d_in[8];
  const float* ln1_b   = (const float*)d_in[9];
  const float* conv2_w = (const float*)d_in[10];
  const float* conv2_b = (const float*)d_in[11];
  const float* ln2_g   = (const float*)d_in[12];
  const float* ln2_b   = (const float*)d_in[13];
  const float* lin_w   = (const float*)d_in[14];
  const float* lin_b   = (const float*)d_in[15];
  const float* pitch_emb   = (const float*)d_in[16];
  const float* energy_emb  = (const float*)d_in[17];
  const float* pitch_bins  = (const float*)d_in[18];
  const float* energy_bins = (const float*)d_in[19];

  float* out      = (float*)d_out;
  float* x_out    = out;                               // 32*4096*512
  float* p_pitch  = out + (size_t)B_ * T_ * D_;
  float* p_energy = p_pitch + B_ * S_;
  float* p_dur    = p_energy + B_ * S_;
  float* p_mellen = p_dur + B_ * S_;
  float* p_mask   = p_mellen + B_;

  // ws: P (16.8MB bf16 padded) | WT1 (4.7MB) | WT2 (4.7MB) | y (33.6MB f32)
  //     | xa (33.6MB f32) | cum (64KB)   total ~93.5MB
  __hip_bfloat16* P   = (__hip_bfloat16*)d_ws;
  __hip_bfloat16* WT1 = P + (size_t)B_ * SP_ * D_;
  __hip_bfloat16* WT2 = WT1 + (size_t)3 * F_ * KK_;
  float* y  = (float*)(WT2 + (size_t)3 * F_ * KK_);
  float* xa = y + (size_t)B_ * S_ * F_;
  int*  cum = (int*)(xa + (size_t)B_ * S_ * D_);

  const dim3 blk256(256), blk128(128), blk512(512);
  const dim3 rowGrid(B_ * S_);               // 16384
  const dim3 convGrid(512);                  // 128 M-tiles x 4 N-tiles
  const dim3 linGrid(B_ * S_ / 4);           // 4096

  zeropad_k<<<dim3(B_ * 2), blk128, 0, stream>>>(P);
  wtrans_k<<<dim3(6 * 24 * 8), blk256, 0, stream>>>(conv1_w, conv2_w, WT1, WT2);

  auto predictor = [&](const float* in, int i, float* pred) {
    topad_k<<<rowGrid, blk128, 0, stream>>>(in, P);
    convmm_k<<<convGrid, blk256, 0, stream>>>(P, WT1 + (size_t)i * F_ * KK_, y);
    ln_pad_k<<<rowGrid, blk256, 0, stream>>>(y, conv1_b + (size_t)i * F_,
                                             ln1_g + (size_t)i * F_,
                                             ln1_b + (size_t)i * F_, P);
    convmm_k<<<convGrid, blk256, 0, stream>>>(P, WT2 + (size_t)i * F_ * KK_, y);
    ln_f32_k<<<rowGrid, blk256, 0, stream>>>(y, conv2_b + (size_t)i * F_,
                                             ln2_g + (size_t)i * F_,
                                             ln2_b + (size_t)i * F_);
    lin_k<<<linGrid, blk256, 0, stream>>>(y, lin_w + (size_t)i * F_, lin_b + i,
                                          srcm, pred);
  };

  predictor(x, 0, p_pitch);
  addemb_k<<<rowGrid, blk128, 0, stream>>>(x, pitch_truth, pitch_bins, pitch_emb, xa);
  predictor(xa, 1, p_energy);
  addemb_k<<<rowGrid, blk128, 0, stream>>>(xa, energy_truth, energy_bins, energy_emb, xa);
  predictor(xa, 2, p_dur);

  scan_k<<<dim3(B_), blk512, 0, stream>>>(dur, cum, p_mellen);
  gather_k<<<dim3(B_ * T_), blk128, 0, stream>>>(xa, cum, x_out);
  maskcopy_k<<<dim3((B_ * T_) / 256), blk256, 0, stream>>>(melm, p_mask);
}